// Round 7
// baseline (216.784 us; speedup 1.0000x reference)
//
#include <hip/hip_runtime.h>

#define BB 4
#define AA 100000
#define MM 32
#define NC 80
#define GX 391                 // ceil(AA/256)
#define NBLK (GX * BB)         // 1564 target blocks
#define FB 3125                // focal blocks
#define FT (FB * 256)          // 800,000 focal threads
#define N4 (BB * AA * (NC/4))  // 8,000,000 float4s == 10 * FT exactly
#define LN2 0.69314718055994530942f

// ws layout (floats): reg_part[NBLK] | pos_part[NBLK](uint) | cls_part[FB]
// Everything written unconditionally each call -> no zero-init, no atomics,
// and no codes array: focal is fully independent of targets.

__device__ __forceinline__ float hw_log2(float x) {
#if defined(__has_builtin)
#if __has_builtin(__builtin_amdgcn_logf)
    return __builtin_amdgcn_logf(x);   // raw v_log_f32 (log2)
#else
    return __log2f(x);
#endif
#else
    return __log2f(x);
#endif
}

__device__ __forceinline__ float clampp(float p) {
    return fminf(fmaxf(p, 1e-4f), 0.9999f);
}
// focal term for label==0, natural-log units
__device__ __forceinline__ float fneg(float p) {
    return 0.75f * p * p * (-LN2 * hw_log2(1.0f - p));
}
// focal term for label==1, natural-log units
__device__ __forceinline__ float fpos(float p) {
    const float q = 1.0f - p;
    return 0.25f * q * q * (-LN2 * hw_log2(p));
}

__global__ __launch_bounds__(256) void targets_kernel(
    const float* __restrict__ anchors,      // AA*4
    const float* __restrict__ annotations,  // BB*MM*5
    const float* __restrict__ regression,   // BB*AA*4
    const float* __restrict__ cls,          // BB*AA*NC (correction reads only)
    float* __restrict__ reg_part,
    unsigned* __restrict__ pos_part)
{
    __shared__ float ann[MM * 5];
    const int b = blockIdx.y;
    const int tid = threadIdx.x;
    if (tid < MM * 5) ann[tid] = annotations[b * MM * 5 + tid];
    __syncthreads();

    const int a = blockIdx.x * 256 + tid;
    float acc = 0.0f;     // reg loss + cls corrections (all summed at the end anyway)
    int pos_cnt = 0;

    if (a < AA) {
        const float4 an = ((const float4*)anchors)[a];
        const float ax1 = an.x, ay1 = an.y, ax2 = an.z, ay2 = an.w;
        // exact IEEE ops (no FMA contraction) so pos/ignore thresholds match numpy bit-for-bit:
        const float area_a = __fmul_rn(__fsub_rn(ax2, ax1), __fsub_rn(ay2, ay1));

        float best_iou = -1.0f;
        int best = 0;
        #pragma unroll
        for (int j = 0; j < MM; ++j) {
            const float bx1 = ann[j * 5 + 0];
            const float by1 = ann[j * 5 + 1];
            const float bx2 = ann[j * 5 + 2];
            const float by2 = ann[j * 5 + 3];
            const float ix1 = fmaxf(ax1, bx1);
            const float iy1 = fmaxf(ay1, by1);
            const float ix2 = fminf(ax2, bx2);
            const float iy2 = fminf(ay2, by2);
            const float iw = fmaxf(__fsub_rn(ix2, ix1), 0.0f);
            const float ih = fmaxf(__fsub_rn(iy2, iy1), 0.0f);
            const float inter = __fmul_rn(iw, ih);
            const float area_b = __fmul_rn(__fsub_rn(bx2, bx1), __fsub_rn(by2, by1));
            const float uni = __fsub_rn(__fadd_rn(area_a, area_b), inter);
            const float iou = __fdiv_rn(inter, fmaxf(uni, 1e-8f));
            if (iou > best_iou) { best_iou = iou; best = j; }  // strict > keeps first max (argmax)
        }

        const bool pos = best_iou >= 0.5f;
        const bool ign = (best_iou > 0.4f) && !pos;
        const float cx = (ax1 + ax2) * 0.5f;
        const float cy = (ay1 + ay2) * 0.5f;
        const bool inside = (cx >= 0.0f) && (cx < 800.0f) && (cy >= 0.0f) && (cy < 800.0f);

        // code: -2 excluded (state==-1), -1 valid negative, 0..79 positive class
        int code = -2;
        if (inside && !ign) code = pos ? (int)ann[best * 5 + 4] : -1;

        if (pos && inside) {                    // state == 1: smooth-L1 reg loss
            pos_cnt = 1;
            const float aw = ax2 - ax1;
            const float ah = ay2 - ay1;
            const float bx1 = ann[best * 5 + 0];
            const float by1 = ann[best * 5 + 1];
            const float bx2 = ann[best * 5 + 2];
            const float by2 = ann[best * 5 + 3];
            float t[4];
            t[0] = ((bx1 - ax1) / aw) / 0.2f;
            t[1] = ((by1 - ay1) / ah) / 0.2f;
            t[2] = ((bx2 - ax2) / aw) / 0.2f;
            t[3] = ((by2 - ay2) / ah) / 0.2f;
            const float* rg = regression + (((size_t)b * AA + a) * 4);
            #pragma unroll
            for (int k = 0; k < 4; ++k) {
                const float d = fabsf(rg[k] - t[k]);
                acc += (d < (1.0f / 9.0f)) ? (4.5f * d * d) : (d - (0.5f / 9.0f));
            }
        }

        // ---- rare correction tail (~1-5% of lanes diverge) ----
        // The focal stream adds fneg for ALL 32M elements. Fix up here:
        if (code == -2) {
            // excluded anchor: subtract all 80 label==0 terms
            const float4* c4 = (const float4*)cls + ((size_t)b * AA + a) * 20;
            #pragma unroll 4
            for (int k = 0; k < 20; ++k) {
                const float4 v = c4[k];
                acc -= fneg(clampp(v.x)) + fneg(clampp(v.y))
                     + fneg(clampp(v.z)) + fneg(clampp(v.w));
            }
        } else if (code >= 0) {
            // positive anchor: labeled column gets fpos instead of fneg
            const float p = clampp(cls[((size_t)b * AA + a) * NC + code]);
            acc += fpos(p) - fneg(p);
        }
    }

    #pragma unroll
    for (int off = 32; off > 0; off >>= 1) {
        acc     += __shfl_down(acc, off);
        pos_cnt += __shfl_down(pos_cnt, off);
    }
    __shared__ float wr[4];
    __shared__ int   wp[4];
    const int wave = tid >> 6, lane = tid & 63;
    if (lane == 0) { wr[wave] = acc; wp[wave] = pos_cnt; }
    __syncthreads();
    if (tid == 0) {
        const int idx = b * GX + blockIdx.x;
        reg_part[idx] = wr[0] + wr[1] + wr[2] + wr[3];
        pos_part[idx] = (unsigned)(wp[0] + wp[1] + wp[2] + wp[3]);
    }
}

// Pure streaming reduce over all 8M float4s — NO data-dependent values anywhere.
// Each thread: 10 float4 loads at affine addresses (consecutive threads ->
// consecutive float4s), issued back-to-back, then math with 4 independent
// accumulators. Structurally identical to a peak-BW float4 reduce.
__global__ __launch_bounds__(256) void focal_kernel(
    const float4* __restrict__ cls4,   // N4
    float* __restrict__ cls_part)
{
    const int t0 = blockIdx.x * 256 + threadIdx.x;
    float4 v[10];
    #pragma unroll
    for (int k = 0; k < 10; ++k) v[k] = cls4[t0 + k * FT];
    __builtin_amdgcn_sched_barrier(0);   // keep all 10 loads in flight

    float s0 = 0.0f, s1 = 0.0f, s2 = 0.0f, s3 = 0.0f;  // log2-space sums of p^2*(-log2(1-p))
    #pragma unroll
    for (int k = 0; k < 10; ++k) {
        const float p0 = clampp(v[k].x);
        const float p1 = clampp(v[k].y);
        const float p2 = clampp(v[k].z);
        const float p3 = clampp(v[k].w);
        s0 -= p0 * p0 * hw_log2(1.0f - p0);
        s1 -= p1 * p1 * hw_log2(1.0f - p1);
        s2 -= p2 * p2 * hw_log2(1.0f - p2);
        s3 -= p3 * p3 * hw_log2(1.0f - p3);
    }
    float csum = (0.75f * LN2) * ((s0 + s1) + (s2 + s3));

    #pragma unroll
    for (int off = 32; off > 0; off >>= 1) csum += __shfl_down(csum, off);
    __shared__ float wc[4];
    const int wave = threadIdx.x >> 6, lane = threadIdx.x & 63;
    if (lane == 0) wc[wave] = csum;
    __syncthreads();
    if (threadIdx.x == 0) cls_part[blockIdx.x] = wc[0] + wc[1] + wc[2] + wc[3];
}

__global__ __launch_bounds__(256) void finalize_kernel(
    const float* __restrict__ reg_part,
    const unsigned* __restrict__ pos_part,
    const float* __restrict__ cls_part,
    float* __restrict__ out)
{
    float cs = 0.0f, rs = 0.0f;
    unsigned pc = 0;
    for (int i = threadIdx.x; i < FB; i += 256) cs += cls_part[i];
    for (int i = threadIdx.x; i < NBLK; i += 256) { rs += reg_part[i]; pc += pos_part[i]; }
    #pragma unroll
    for (int off = 32; off > 0; off >>= 1) {
        cs += __shfl_down(cs, off);
        rs += __shfl_down(rs, off);
        pc += __shfl_down(pc, off);
    }
    __shared__ float wc[4], wr[4];
    __shared__ unsigned wp[4];
    const int wave = threadIdx.x >> 6, lane = threadIdx.x & 63;
    if (lane == 0) { wc[wave] = cs; wr[wave] = rs; wp[wave] = pc; }
    __syncthreads();
    if (threadIdx.x == 0) {
        const float csum = wc[0] + wc[1] + wc[2] + wc[3];
        const float rsum = wr[0] + wr[1] + wr[2] + wr[3];
        const float np = fmaxf((float)(wp[0] + wp[1] + wp[2] + wp[3]), 1.0f);
        out[0] = (csum + rsum) / np;
    }
}

extern "C" void kernel_launch(void* const* d_in, const int* in_sizes, int n_in,
                              void* d_out, int out_size, void* d_ws, size_t ws_size,
                              hipStream_t stream)
{
    const float* classification = (const float*)d_in[0];  // BB*AA*NC
    const float* regression     = (const float*)d_in[1];  // BB*AA*4
    const float* anchors        = (const float*)d_in[2];  // AA*4
    const float* annotations    = (const float*)d_in[3];  // BB*MM*5
    float* out = (float*)d_out;

    float*    reg_part = (float*)d_ws;
    unsigned* pos_part = (unsigned*)d_ws + NBLK;
    float*    cls_part = (float*)d_ws + 2 * NBLK;

    focal_kernel<<<FB, 256, 0, stream>>>((const float4*)classification, cls_part);
    dim3 gA(GX, BB);
    targets_kernel<<<gA, 256, 0, stream>>>(anchors, annotations, regression,
                                           classification, reg_part, pos_part);
    finalize_kernel<<<1, 256, 0, stream>>>(reg_part, pos_part, cls_part, out);
}